// Round 1
// baseline (73979.163 us; speedup 1.0000x reference)
//
#include <hip/hip_runtime.h>
#include <hip/hip_bf16.h>
#include <hip/hip_cooperative_groups.h>

namespace cg = cooperative_groups;

#define B_ 128
#define T_ 1024
#define I_ 256
#define H_ 1024
#define O_ 128

typedef __attribute__((ext_vector_type(4))) float f32x4;
typedef __attribute__((ext_vector_type(8))) short s16x8;

__device__ __forceinline__ unsigned short f2bf(float f){
  union { float f; unsigned int u; } a; a.f = f;
  unsigned int r = a.u + 0x7FFFu + ((a.u >> 16) & 1u);
  return (unsigned short)(r >> 16);
}
__device__ __forceinline__ float sigmf(float x){ return 1.f/(1.f+__expf(-x)); }
__device__ __forceinline__ float tanhf_(float x){ return 2.f/(1.f+__expf(-2.f*x)) - 1.f; }

// ---- prep kernels -------------------------------------------------------

__global__ void k_cast_x(const float* __restrict__ x, unsigned short* __restrict__ xb, int n4){
  int i = blockIdx.x*blockDim.x + threadIdx.x;
  if (i >= n4) return;
  f32x4 v = reinterpret_cast<const f32x4*>(x)[i];
  ushort4 o;
  o.x = f2bf(v[0]); o.y = f2bf(v[1]); o.z = f2bf(v[2]); o.w = f2bf(v[3]);
  reinterpret_cast<ushort4*>(xb)[i] = o;
}

// W0cat LDS-layout: [wg 256][kblk 160][row 16][8] bf16, k = [w_ih0 (256) | w_hh0 (1024)]
__global__ void k_prep_w0(const float* __restrict__ wih, const float* __restrict__ whh,
                          unsigned short* __restrict__ out){
  int n = blockIdx.x*256 + threadIdx.x;           // 256*160*16*8 = 5242880
  int j = n & 7, r = (n >> 3) & 15;
  int t = n >> 7;
  int kb = t % 160, gw = t / 160;
  int k = kb*8 + j;
  int grow = (r >> 2)*H_ + gw*4 + (r & 3);
  float v = (k < I_) ? wih[grow*I_ + k] : whh[grow*H_ + (k - I_)];
  out[n] = f2bf(v);
}

// W1cat LDS-layout: [wg 256][kblk 256][row 16][8] bf16, k = [w_ih1 (1024) | w_hh1 (1024)]
__global__ void k_prep_w1(const float* __restrict__ wih, const float* __restrict__ whh,
                          unsigned short* __restrict__ out){
  int n = blockIdx.x*256 + threadIdx.x;           // 256*256*16*8 = 8388608
  int j = n & 7, r = (n >> 3) & 15;
  int t = n >> 7;
  int kb = t & 255, gw = t >> 8;
  int k = kb*8 + j;
  int grow = (r >> 2)*H_ + gw*4 + (r & 3);
  float v = (k < H_) ? wih[grow*H_ + k] : whh[grow*H_ + (k - H_)];
  out[n] = f2bf(v);
}

__global__ void k_prep_b(const float* __restrict__ bi0, const float* __restrict__ bh0,
                         const float* __restrict__ bi1, const float* __restrict__ bh1,
                         float* __restrict__ b0, float* __restrict__ b1){
  int n = blockIdx.x*256 + threadIdx.x;           // 8192
  int layer = n >> 12; int rem = n & 4095;
  int gw = rem >> 4, r = rem & 15;
  int grow = (r >> 2)*H_ + gw*4 + (r & 3);
  if (layer == 0) b0[rem] = bi0[grow] + bh0[grow];
  else            b1[rem] = bi1[grow] + bh1[grow];
}

// ---- persistent LSTM kernel --------------------------------------------

struct KArgs {
  const unsigned short* xb;   // bf16 x, may be null
  const float* x32;           // fp32 x fallback
  const unsigned short* w0l;
  const unsigned short* w1l;
  const float* b0l;
  const float* b1l;
  unsigned short* h0;         // [2][B][H] bf16
  unsigned short* h1;         // [2][B][H] bf16
  float* hfin;                // [B][H] fp32
  const float* wout;
  const float* bout;
  float* y;
};

__device__ __forceinline__ void reduce_update(const float* __restrict__ sG,
    const float* __restrict__ sB, float* __restrict__ sC,
    unsigned short* __restrict__ hw, float* __restrict__ hfin,
    int uglob, int tid, bool fin)
{
  #pragma unroll
  for (int half = 0; half < 2; ++half){
    int it = tid + half*256;
    int b = it >> 2, u = it & 3;
    float pre[4];
    #pragma unroll
    for (int gg = 0; gg < 4; ++gg){
      int n = gg*4 + u;
      pre[gg] = sB[n] + sG[b*17 + n] + sG[(128 + b)*17 + n]
                      + sG[(256 + b)*17 + n] + sG[(384 + b)*17 + n];
    }
    float iv = sigmf(pre[0]);
    float fv = sigmf(pre[1]);
    float gv = tanhf_(pre[2]);
    float ov = sigmf(pre[3]);
    float c  = sC[b*4 + u];
    float cn = fv*c + iv*gv;
    sC[b*4 + u] = cn;
    float h = ov*tanhf_(cn);
    hw[b*H_ + uglob + u] = f2bf(h);
    if (fin) hfin[b*H_ + uglob + u] = h;
  }
}

__global__ void __launch_bounds__(256, 1) k_lstm(KArgs a){
  cg::grid_group grid = cg::this_grid();
  extern __shared__ char smem[];
  unsigned short* sW0 = (unsigned short*)smem;             // 40960 B
  unsigned short* sW1 = (unsigned short*)(smem + 40960);   // 65536 B
  float* sB0 = (float*)(smem + 106496);                    // 16 f
  float* sB1 = sB0 + 16;                                   // 16 f
  float* sC0 = sB1 + 16;                                   // 512 f
  float* sC1 = sC0 + 512;                                  // 512 f
  float* sG  = sC1 + 512;                                  // 4*128*17 = 8704 f
  // total = 145536 B

  const int tid  = threadIdx.x;
  const int gwg  = blockIdx.x;
  const int wv   = tid >> 6;
  const int lane = tid & 63;
  const int lrow = lane & 15;
  const int kgrp = lane >> 4;
  const int koff = kgrp * 8;
  const int uglob = gwg * 4;

  // stage weights + init c
  {
    const s16x8* s0 = (const s16x8*)a.w0l + gwg*2560;
    s16x8* d0 = (s16x8*)sW0;
    for (int i = tid; i < 2560; i += 256) d0[i] = s0[i];
    const s16x8* s1 = (const s16x8*)a.w1l + gwg*4096;
    s16x8* d1 = (s16x8*)sW1;
    for (int i = tid; i < 4096; i += 256) d1[i] = s1[i];
    if (tid < 16){ sB0[tid] = a.b0l[gwg*16 + tid]; sB1[tid] = a.b1l[gwg*16 + tid]; }
    for (int i = tid; i < 1024; i += 256) sC0[i] = 0.f;  // sC0,sC1 contiguous
  }
  __syncthreads();

  int brow[8], hoff[8], xoff[8];
  #pragma unroll
  for (int bt = 0; bt < 8; ++bt){
    brow[bt] = bt*16 + lrow;
    hoff[bt] = brow[bt]*H_;
    xoff[bt] = brow[bt]*(T_*I_);
  }

  const int  kbase1 = (wv & 1)*512;
  const bool useh0  = (wv < 2);

  for (int p = 0; p <= T_; ++p){
    const int parW = p & 1;
    const unsigned short* h0r = a.h0 + (parW^1)*(B_*H_);  // h0_{p-1}
    const unsigned short* h1r = a.h1 + parW   *(B_*H_);   // h1_{p-2}
    unsigned short* h0w = a.h0 + parW   *(B_*H_);         // h0_p
    unsigned short* h1w = a.h1 + (parW^1)*(B_*H_);        // h1_{p-1}

    if (p > 0){
      // layer 1, step p-1: gates1 = [h0_{p-1} | h1_{p-2}] @ W1cat^T   (K=2048)
      f32x4 acc[8];
      #pragma unroll
      for (int bt = 0; bt < 8; ++bt) acc[bt] = {0.f,0.f,0.f,0.f};
      const unsigned short* src = useh0 ? h0r : h1r;
      const unsigned short* wp  = sW1 + wv*8192 + kgrp*128 + lrow*8;
      #pragma unroll 2
      for (int kc = 0; kc < 16; ++kc){
        s16x8 bfr = *(const s16x8*)(wp + kc*512);
        const unsigned short* sp = src + kbase1 + kc*32 + koff;
        #pragma unroll
        for (int bt = 0; bt < 8; ++bt){
          s16x8 af = *(const s16x8*)(sp + hoff[bt]);
          acc[bt] = __builtin_amdgcn_mfma_f32_16x16x32_bf16(af, bfr, acc[bt], 0, 0, 0);
        }
      }
      #pragma unroll
      for (int bt = 0; bt < 8; ++bt){
        #pragma unroll
        for (int r = 0; r < 4; ++r)
          sG[(wv*128 + bt*16 + kgrp*4 + r)*17 + lrow] = acc[bt][r];
      }
      __syncthreads();
      reduce_update(sG, sB1, sC1, h1w, a.hfin, uglob, tid, p == T_);
      __syncthreads();
    }

    if (p < T_){
      // layer 0, step p: gates0 = [x_p | h0_{p-1}] @ W0cat^T   (K=1280)
      f32x4 acc[8];
      #pragma unroll
      for (int bt = 0; bt < 8; ++bt) acc[bt] = {0.f,0.f,0.f,0.f};
      const unsigned short* wp = sW0 + wv*5120 + kgrp*128 + lrow*8;
      for (int kcl = 0; kcl < 10; ++kcl){
        const int kc = wv*10 + kcl;
        const int k  = kc*32 + koff;
        s16x8 bfr = *(const s16x8*)(wp + kcl*512);
        if (kc < 8){
          if (a.xb){
            const unsigned short* sp = a.xb + p*I_ + k;
            #pragma unroll
            for (int bt = 0; bt < 8; ++bt){
              s16x8 af = *(const s16x8*)(sp + xoff[bt]);
              acc[bt] = __builtin_amdgcn_mfma_f32_16x16x32_bf16(af, bfr, acc[bt], 0, 0, 0);
            }
          } else {
            const float* sp = a.x32 + p*I_ + k;
            #pragma unroll
            for (int bt = 0; bt < 8; ++bt){
              f32x4 f0 = *(const f32x4*)(sp + xoff[bt]);
              f32x4 f1 = *(const f32x4*)(sp + xoff[bt] + 4);
              union { s16x8 v; unsigned short u[8]; } t2;
              #pragma unroll
              for (int j2 = 0; j2 < 4; ++j2){ t2.u[j2] = f2bf(f0[j2]); t2.u[4+j2] = f2bf(f1[j2]); }
              acc[bt] = __builtin_amdgcn_mfma_f32_16x16x32_bf16(t2.v, bfr, acc[bt], 0, 0, 0);
            }
          }
        } else {
          const unsigned short* sp = h0r + (k - I_);
          #pragma unroll
          for (int bt = 0; bt < 8; ++bt){
            s16x8 af = *(const s16x8*)(sp + hoff[bt]);
            acc[bt] = __builtin_amdgcn_mfma_f32_16x16x32_bf16(af, bfr, acc[bt], 0, 0, 0);
          }
        }
      }
      #pragma unroll
      for (int bt = 0; bt < 8; ++bt){
        #pragma unroll
        for (int r = 0; r < 4; ++r)
          sG[(wv*128 + bt*16 + kgrp*4 + r)*17 + lrow] = acc[bt][r];
      }
      __syncthreads();
      reduce_update(sG, sB0, sC0, h0w, nullptr, uglob, tid, false);
      __syncthreads();
    }

    grid.sync();
  }

  // output: y = h_last @ w_out^T + b_out, fp32, on WGs 0..63
  if (gwg < 64){
    const int b = (gwg >> 3)*16 + (tid >> 4);
    const int o = (gwg & 7)*16 + (tid & 15);
    const f32x4* hr = (const f32x4*)(a.hfin + b*H_);
    const f32x4* wr = (const f32x4*)(a.wout + o*H_);
    float s = a.bout[o];
    for (int k2 = 0; k2 < H_/4; ++k2){
      f32x4 hv = hr[k2], wv2 = wr[k2];
      s += hv[0]*wv2[0] + hv[1]*wv2[1] + hv[2]*wv2[2] + hv[3]*wv2[3];
    }
    a.y[b*O_ + o] = s;
  }
}

// ---- host ---------------------------------------------------------------

extern "C" void kernel_launch(void* const* d_in, const int* in_sizes, int n_in,
                              void* d_out, int out_size, void* d_ws, size_t ws_size,
                              hipStream_t stream){
  const float* x    = (const float*)d_in[0];
  const float* wih0 = (const float*)d_in[1];
  const float* whh0 = (const float*)d_in[2];
  const float* bih0 = (const float*)d_in[3];
  const float* bhh0 = (const float*)d_in[4];
  const float* wih1 = (const float*)d_in[5];
  const float* whh1 = (const float*)d_in[6];
  const float* bih1 = (const float*)d_in[7];
  const float* bhh1 = (const float*)d_in[8];
  const float* wout = (const float*)d_in[9];
  const float* bout = (const float*)d_in[10];
  float* y = (float*)d_out;

  char* ws = (char*)d_ws;
  size_t off = 0;
  auto alloc = [&](size_t n){ char* p = ws + off; off += (n + 255) & ~(size_t)255; return p; };

  unsigned short* w0l = (unsigned short*)alloc((size_t)256*160*16*8*2);
  unsigned short* w1l = (unsigned short*)alloc((size_t)256*256*16*8*2);
  float* b0l  = (float*)alloc(256*16*4);
  float* b1l  = (float*)alloc(256*16*4);
  unsigned short* h0 = (unsigned short*)alloc((size_t)2*B_*H_*2);
  unsigned short* h1 = (unsigned short*)alloc((size_t)2*B_*H_*2);
  float* hfin = (float*)alloc((size_t)B_*H_*4);
  unsigned short* xb = nullptr;
  size_t xb_bytes = (size_t)B_*T_*I_*2;
  if (ws_size >= off + xb_bytes + 256) xb = (unsigned short*)alloc(xb_bytes);

  hipMemsetAsync(h0, 0, (size_t)2*B_*H_*2, stream);
  hipMemsetAsync(h1, 0, (size_t)2*B_*H_*2, stream);

  if (xb) k_cast_x<<<dim3((B_*T_*I_/4 + 255)/256), dim3(256), 0, stream>>>(x, xb, B_*T_*I_/4);
  k_prep_w0<<<dim3(5242880/256), dim3(256), 0, stream>>>(wih0, whh0, w0l);
  k_prep_w1<<<dim3(8388608/256), dim3(256), 0, stream>>>(wih1, whh1, w1l);
  k_prep_b<<<dim3(32), dim3(256), 0, stream>>>(bih0, bhh0, bih1, bhh1, b0l, b1l);

  KArgs args;
  args.xb = xb; args.x32 = x;
  args.w0l = w0l; args.w1l = w1l; args.b0l = b0l; args.b1l = b1l;
  args.h0 = h0; args.h1 = h1; args.hfin = hfin;
  args.wout = wout; args.bout = bout; args.y = y;

  (void)hipFuncSetAttribute((const void*)k_lstm,
                            hipFuncAttributeMaxDynamicSharedMemorySize, 145536);
  void* kp[] = { (void*)&args };
  hipLaunchCooperativeKernel((void*)k_lstm, dim3(256), dim3(256), kp, 145536, stream);
}

// Round 2
// 72032.300 us; speedup vs baseline: 1.0270x; 1.0270x over previous
//
#include <hip/hip_runtime.h>
#include <hip/hip_bf16.h>
#include <hip/hip_cooperative_groups.h>

namespace cg = cooperative_groups;

#define B_ 128
#define T_ 1024
#define I_ 256
#define H_ 1024
#define O_ 128
#define D_ 6   // staging pipeline depth (steps ahead); vmcnt threshold = 2*(D_-1)

typedef __attribute__((ext_vector_type(4))) float f32x4;
typedef __attribute__((ext_vector_type(8))) short s16x8;

__device__ __forceinline__ unsigned short f2bf(float f){
  union { float f; unsigned int u; } a; a.f = f;
  unsigned int r = a.u + 0x7FFFu + ((a.u >> 16) & 1u);
  return (unsigned short)(r >> 16);
}
__device__ __forceinline__ float sigmf(float x){ return 1.f/(1.f+__expf(-x)); }
__device__ __forceinline__ float tanhf_(float x){ return 2.f/(1.f+__expf(-2.f*x)) - 1.f; }

typedef const __attribute__((address_space(1))) void* gptr_t;
typedef __attribute__((address_space(3))) void* lptr_t;

// async global->LDS, 16B per lane; LDS dest = wave-uniform base + lane*16
__device__ __forceinline__ void gload16(const void* g, void* l){
  __builtin_amdgcn_global_load_lds((gptr_t)(unsigned long long)g,
                                   (lptr_t)(unsigned int)(unsigned long long)l,
                                   16, 0, 0);
}

// ---- prep kernels -------------------------------------------------------

__global__ void k_cast_x(const float* __restrict__ x, unsigned short* __restrict__ xb, int n4){
  int i = blockIdx.x*blockDim.x + threadIdx.x;
  if (i >= n4) return;
  f32x4 v = reinterpret_cast<const f32x4*>(x)[i];
  ushort4 o;
  o.x = f2bf(v[0]); o.y = f2bf(v[1]); o.z = f2bf(v[2]); o.w = f2bf(v[3]);
  reinterpret_cast<ushort4*>(xb)[i] = o;
}

// W0cat layout: [wg 256][kblk 160][row 16][8] bf16, k = [w_ih0 (256) | w_hh0 (1024)]
__global__ void k_prep_w0(const float* __restrict__ wih, const float* __restrict__ whh,
                          unsigned short* __restrict__ out){
  int n = blockIdx.x*256 + threadIdx.x;           // 5242880
  int j = n & 7, r = (n >> 3) & 15;
  int t = n >> 7;
  int kb = t % 160, gw = t / 160;
  int k = kb*8 + j;
  int grow = (r >> 2)*H_ + gw*4 + (r & 3);
  float v = (k < I_) ? wih[grow*I_ + k] : whh[grow*H_ + (k - I_)];
  out[n] = f2bf(v);
}

// W1cat layout: [wg 256][kblk 256][row 16][8] bf16, k = [w_ih1 (1024) | w_hh1 (1024)]
__global__ void k_prep_w1(const float* __restrict__ wih, const float* __restrict__ whh,
                          unsigned short* __restrict__ out){
  int n = blockIdx.x*256 + threadIdx.x;           // 8388608
  int j = n & 7, r = (n >> 3) & 15;
  int t = n >> 7;
  int kb = t & 255, gw = t >> 8;
  int k = kb*8 + j;
  int grow = (r >> 2)*H_ + gw*4 + (r & 3);
  float v = (k < H_) ? wih[grow*H_ + k] : whh[grow*H_ + (k - H_)];
  out[n] = f2bf(v);
}

__global__ void k_prep_b(const float* __restrict__ bi0, const float* __restrict__ bh0,
                         const float* __restrict__ bi1, const float* __restrict__ bh1,
                         float* __restrict__ b0, float* __restrict__ b1){
  int n = blockIdx.x*256 + threadIdx.x;           // 8192
  int layer = n >> 12; int rem = n & 4095;
  int gw = rem >> 4, r = rem & 15;
  int grow = (r >> 2)*H_ + gw*4 + (r & 3);
  if (layer == 0) b0[rem] = bi0[grow] + bh0[grow];
  else            b1[rem] = bi1[grow] + bh1[grow];
}

// ---- persistent LSTM kernel --------------------------------------------

struct KArgs {
  const unsigned short* xb;   // bf16 x (may be null if ws too small)
  const float* x32;
  const unsigned short* w0l;
  const unsigned short* w1l;
  const float* b0l;
  const float* b1l;
  unsigned short* h0;         // [2][B][H] bf16
  unsigned short* h1;         // [2][B][H] bf16
  float* hfin;                // [B][H] fp32
  const float* wout;
  const float* bout;
  float* y;
};

// In-register gate epilogue. acc[btl][r] holds pre-act for
// (batch=(wv*2+btl)*16 + (lane>>4)*4 + r, gate-row = lane&15).
// Gate rows pack: gate = (lane&15)>>2, unit = lane&3. The 4 gates of a unit
// live in lanes {l^0,l^4,l^8,l^12}; gather via shfl_xor; all 4 lanes keep a
// redundant (bit-identical) copy of c; lane with g0==0 writes h.
__device__ __forceinline__ void epi(f32x4 (&acc)[2], float (&cs)[2][4], float bias,
                                    unsigned short* __restrict__ hw,
                                    float* __restrict__ hfin,
                                    int wv, int lane, int gwg){
  const int u  = lane & 3;
  const int g0 = (lane >> 2) & 3;
  const int bq = lane >> 4;
  #pragma unroll
  for (int btl = 0; btl < 2; ++btl){
    #pragma unroll
    for (int r = 0; r < 4; ++r){
      float pre = acc[btl][r] + bias;
      float q1 = __shfl_xor(pre, 4);
      float q2 = __shfl_xor(pre, 8);
      float q3 = __shfl_xor(pre, 12);
      // value q_m carries gate index g0^m; gate[j] = q_{g0^j}
      float iv = (g0==0)?pre:((g0==1)?q1:((g0==2)?q2:q3));
      float fv = (g0==1)?pre:((g0==0)?q1:((g0==3)?q2:q3));
      float gv = (g0==2)?pre:((g0==3)?q1:((g0==0)?q2:q3));
      float ov = (g0==3)?pre:((g0==2)?q1:((g0==1)?q2:q3));
      iv = sigmf(iv); fv = sigmf(fv); gv = tanhf_(gv); ov = sigmf(ov);
      float cn = fv*cs[btl][r] + iv*gv;
      cs[btl][r] = cn;
      float h = ov*tanhf_(cn);
      if (g0 == 0){
        int idx = ((wv*2+btl)*16 + bq*4 + r)*H_ + (gwg<<2) + u;
        hw[idx] = f2bf(h);
        if (hfin) hfin[idx] = h;
      }
    }
  }
}

__global__ void __launch_bounds__(256, 1) k_lstm(KArgs a){
  cg::grid_group grid = cg::this_grid();
  extern __shared__ char smem[];
  unsigned short* sW0 = (unsigned short*)smem;             // 40960 B
  unsigned short* sW1 = (unsigned short*)(smem + 40960);   // 65536 B  -> 106496
  char* sStage = smem + 106496;                            // 4*D_*2048 = 49152 -> 155648
  char* sDump  = smem + 155648;                            // 2048 (dummy-load target)
  float* sB    = (float*)(smem + 157696);                  // 32 f -> total 157824

  const int tid  = threadIdx.x;
  const int gwg  = blockIdx.x;
  const int wv   = tid >> 6;
  const int lane = tid & 63;
  const int lrow = lane & 15;
  const int kgrp = lane >> 4;

  // stage weights (once, resident for all 1025 phases)
  {
    const s16x8* s0 = (const s16x8*)a.w0l + gwg*2560;
    s16x8* d0 = (s16x8*)sW0;
    for (int i = tid; i < 2560; i += 256) d0[i] = s0[i];
    const s16x8* s1 = (const s16x8*)a.w1l + gwg*4096;
    s16x8* d1 = (s16x8*)sW1;
    for (int i = tid; i < 4096; i += 256) d1[i] = s1[i];
    if (tid < 16){ sB[tid] = a.b0l[gwg*16 + tid]; sB[16 + tid] = a.b1l[gwg*16 + tid]; }
  }
  __syncthreads();

  const float bias0 = sB[lrow];
  const float bias1 = sB[16 + lrow];
  float c0s[2][4] = {{0,0,0,0},{0,0,0,0}};
  float c1s[2][4] = {{0,0,0,0},{0,0,0,0}};

  for (int p = 0; p <= T_; ++p){
    const int parW = p & 1;
    const unsigned short* __restrict__ h0r = a.h0 + (parW^1)*(B_*H_);  // h0_{p-1}
    const unsigned short* __restrict__ h1r = a.h1 + parW   *(B_*H_);   // h1_{p-2}
    unsigned short* __restrict__ h0w = a.h0 + parW   *(B_*H_);         // h0_p
    unsigned short* __restrict__ h1w = a.h1 + (parW^1)*(B_*H_);        // h1_{p-1}
    const int n1 = (p > 0) ? 64 : 0;                 // layer-1 steps (kc over K=2048)
    const int ns = n1 + ((p < T_) ? 40 : 0);         // + layer-0 steps (K=1280)

    // issue the 2 async fragment loads (btl=0,1) for step i into ring slot
    auto issue = [&](int i, int slot){
      #pragma unroll
      for (int btl = 0; btl < 2; ++btl){
        char* dst;
        const unsigned short* src;
        if (i >= ns){ dst = sDump; src = a.h0 + lane*8; }        // drain dummy
        else {
          dst = sStage + ((((wv*D_ + slot) << 1) + btl) << 10);
          const int row16 = (wv*2 + btl)*16 + lrow;
          if (i < n1){                                           // layer 1
            const unsigned short* s = (i < 32) ? h0r : h1r;
            src = s + row16*H_ + ((i & 31) << 5) + (kgrp << 3);
          } else {
            const int kc = i - n1;                               // layer 0
            if (kc < 8){
              if (a.xb) src = a.xb + (size_t)row16*(T_*I_) + p*I_ + (kc << 5) + (kgrp << 3);
              else { dst = sDump; src = a.h0 + lane*8; }         // f32 direct at consume
            } else {
              src = h0r + row16*H_ + ((kc - 8) << 5) + (kgrp << 3);
            }
          }
        }
        gload16(src, dst);
      }
    };

    #pragma unroll
    for (int i = 0; i < D_; ++i) issue(i, i);        // prologue: fill pipeline

    f32x4 z = {0.f, 0.f, 0.f, 0.f};
    f32x4 acc1[2] = {z, z};
    f32x4 acc0[2] = {z, z};

    int slot = 0;
    for (int i = 0; i < ns; ++i){
      // wait until step i's 2 loads landed (2*(D_-1) newer may remain in flight)
      asm volatile("s_waitcnt vmcnt(10)" ::: "memory");
      const char* sb = sStage + (size_t)((wv*D_ + slot) << 11);
      s16x8 af0 = *(const s16x8*)(sb + (lane << 4));
      s16x8 af1 = *(const s16x8*)(sb + 1024 + (lane << 4));
      if (i < n1){
        s16x8 wf = *(const s16x8*)(sW1 + (i << 9) + (lane << 3));
        acc1[0] = __builtin_amdgcn_mfma_f32_16x16x32_bf16(af0, wf, acc1[0], 0, 0, 0);
        acc1[1] = __builtin_amdgcn_mfma_f32_16x16x32_bf16(af1, wf, acc1[1], 0, 0, 0);
      } else {
        const int kc = i - n1;
        s16x8 wf = *(const s16x8*)(sW0 + (kc << 9) + (lane << 3));
        if (kc < 8 && a.xb == nullptr){                          // fallback: x fp32 direct
          #pragma unroll
          for (int btl = 0; btl < 2; ++btl){
            const float* sp = a.x32 + (size_t)((wv*2 + btl)*16 + lrow)*(T_*I_)
                            + p*I_ + (kc << 5) + (kgrp << 3);
            f32x4 f0 = *(const f32x4*)sp;
            f32x4 f1 = *(const f32x4*)(sp + 4);
            union { s16x8 v; unsigned short us[8]; } t2;
            #pragma unroll
            for (int j2 = 0; j2 < 4; ++j2){ t2.us[j2] = f2bf(f0[j2]); t2.us[4+j2] = f2bf(f1[j2]); }
            if (btl == 0) af0 = t2.v; else af1 = t2.v;
          }
        }
        acc0[0] = __builtin_amdgcn_mfma_f32_16x16x32_bf16(af0, wf, acc0[0], 0, 0, 0);
        acc0[1] = __builtin_amdgcn_mfma_f32_16x16x32_bf16(af1, wf, acc0[1], 0, 0, 0);
      }
      issue(i + D_, slot);
      slot = (slot == D_-1) ? 0 : slot + 1;
      if (i == n1 - 1)
        epi(acc1, c1s, bias1, h1w, (p == T_) ? a.hfin : nullptr, wv, lane, gwg);
    }
    if (p < T_)
      epi(acc0, c0s, bias0, h0w, nullptr, wv, lane, gwg);

    grid.sync();   // drains vmcnt + device fence; publishes h0_p / h1_{p-1}
  }

  // output: y = h_last @ w_out^T + b_out (fp32), on WGs 0..63
  if (gwg < 64){
    const int b = (gwg >> 3)*16 + (tid >> 4);
    const int o = (gwg & 7)*16 + (tid & 15);
    const f32x4* hr = (const f32x4*)(a.hfin + b*H_);
    const f32x4* wr = (const f32x4*)(a.wout + o*H_);
    float s = a.bout[o];
    for (int k2 = 0; k2 < H_/4; ++k2){
      f32x4 hv = hr[k2], wv2 = wr[k2];
      s += hv[0]*wv2[0] + hv[1]*wv2[1] + hv[2]*wv2[2] + hv[3]*wv2[3];
    }
    a.y[b*O_ + o] = s;
  }
}

// ---- host ---------------------------------------------------------------

extern "C" void kernel_launch(void* const* d_in, const int* in_sizes, int n_in,
                              void* d_out, int out_size, void* d_ws, size_t ws_size,
                              hipStream_t stream){
  const float* x    = (const float*)d_in[0];
  const float* wih0 = (const float*)d_in[1];
  const float* whh0 = (const float*)d_in[2];
  const float* bih0 = (const float*)d_in[3];
  const float* bhh0 = (const float*)d_in[4];
  const float* wih1 = (const float*)d_in[5];
  const float* whh1 = (const float*)d_in[6];
  const float* bih1 = (const float*)d_in[7];
  const float* bhh1 = (const float*)d_in[8];
  const float* wout = (const float*)d_in[9];
  const float* bout = (const float*)d_in[10];
  float* y = (float*)d_out;

  char* ws = (char*)d_ws;
  size_t off = 0;
  auto alloc = [&](size_t n){ char* p = ws + off; off += (n + 255) & ~(size_t)255; return p; };

  unsigned short* w0l = (unsigned short*)alloc((size_t)256*160*16*8*2);
  unsigned short* w1l = (unsigned short*)alloc((size_t)256*256*16*8*2);
  float* b0l  = (float*)alloc(256*16*4);
  float* b1l  = (float*)alloc(256*16*4);
  unsigned short* h0 = (unsigned short*)alloc((size_t)2*B_*H_*2);
  unsigned short* h1 = (unsigned short*)alloc((size_t)2*B_*H_*2);
  float* hfin = (float*)alloc((size_t)B_*H_*4);
  unsigned short* xb = nullptr;
  size_t xb_bytes = (size_t)B_*T_*I_*2;
  if (ws_size >= off + xb_bytes + 256) xb = (unsigned short*)alloc(xb_bytes);

  hipMemsetAsync(h0, 0, (size_t)2*B_*H_*2, stream);
  hipMemsetAsync(h1, 0, (size_t)2*B_*H_*2, stream);

  if (xb) k_cast_x<<<dim3((B_*T_*I_/4 + 255)/256), dim3(256), 0, stream>>>(x, xb, B_*T_*I_/4);
  k_prep_w0<<<dim3(5242880/256), dim3(256), 0, stream>>>(wih0, whh0, w0l);
  k_prep_w1<<<dim3(8388608/256), dim3(256), 0, stream>>>(wih1, whh1, w1l);
  k_prep_b<<<dim3(32), dim3(256), 0, stream>>>(bih0, bhh0, bih1, bhh1, b0l, b1l);

  KArgs args;
  args.xb = xb; args.x32 = x;
  args.w0l = w0l; args.w1l = w1l; args.b0l = b0l; args.b1l = b1l;
  args.h0 = h0; args.h1 = h1; args.hfin = hfin;
  args.wout = wout; args.bout = bout; args.y = y;

  (void)hipFuncSetAttribute((const void*)k_lstm,
                            hipFuncAttributeMaxDynamicSharedMemorySize, 157824);
  void* kp[] = { (void*)&args };
  hipLaunchCooperativeKernel((void*)k_lstm, dim3(256), dim3(256), kp, 157824, stream);
}